// Round 1
// baseline (206.620 us; speedup 1.0000x reference)
//
#include <hip/hip_runtime.h>

#define D_FEAT 64

// One wave (64 lanes) per contiguous edge range. lane = feature index.
// edge_dst is sorted, so equal destinations are contiguous: accumulate in a
// register while dst is unchanged, flush with atomicAdd at run boundaries.
__global__ __launch_bounds__(256) void gcn_scatter_kernel(
    const float* __restrict__ feat,
    const float* __restrict__ edge_weight,
    const int* __restrict__ edge_src,
    const int* __restrict__ edge_dst,
    float* __restrict__ out,
    int n_edges, int edges_per_wave) {
  const int wave = (blockIdx.x * blockDim.x + threadIdx.x) >> 6;
  const int lane = threadIdx.x & 63;

  long e0 = (long)wave * edges_per_wave;
  long e1 = e0 + edges_per_wave;
  if (e1 > n_edges) e1 = n_edges;
  if (e0 >= e1) return;

  float acc = 0.0f;
  int cur_dst = edge_dst[e0];

  for (long e = e0; e < e1; ++e) {
    const int d = edge_dst[e];          // uniform across wave -> broadcast
    if (d != cur_dst) {
      atomicAdd(&out[(long)cur_dst * D_FEAT + lane], acc);
      acc = 0.0f;
      cur_dst = d;
    }
    const int s = edge_src[e];          // uniform across wave
    const float w = edge_weight[e];     // uniform across wave
    acc = fmaf(feat[(long)s * D_FEAT + lane], w, acc);  // coalesced 256B row
  }
  atomicAdd(&out[(long)cur_dst * D_FEAT + lane], acc);
}

extern "C" void kernel_launch(void* const* d_in, const int* in_sizes, int n_in,
                              void* d_out, int out_size, void* d_ws, size_t ws_size,
                              hipStream_t stream) {
  const float* feat        = (const float*)d_in[0];
  const float* edge_weight = (const float*)d_in[1];
  const int*   edge_src    = (const int*)d_in[2];
  const int*   edge_dst    = (const int*)d_in[3];
  float* out = (float*)d_out;

  const int n_edges = in_sizes[1];  // E = 1,250,000

  // Output is poisoned before every timed launch -> zero it.
  hipMemsetAsync(d_out, 0, (size_t)out_size * sizeof(float), stream);

  // 2048 blocks x 256 threads = 8192 waves; ~153 edges per wave.
  const int blocks = 2048;
  const int waves = blocks * (256 / 64);
  const int edges_per_wave = (n_edges + waves - 1) / waves;

  gcn_scatter_kernel<<<blocks, 256, 0, stream>>>(
      feat, edge_weight, edge_src, edge_dst, out, n_edges, edges_per_wave);
}

// Round 2
// 127.220 us; speedup vs baseline: 1.6241x; 1.6241x over previous
//
#include <hip/hip_runtime.h>

#define D_FEAT 64

// Kernel 1: row_ptr[v] = lower_bound(edge_dst, v) via parallel binary search.
// edge_dst is sorted. row_ptr lives in d_ws (rebuilt every launch; ws is poisoned).
__global__ __launch_bounds__(256) void build_rowptr_kernel(
    const int* __restrict__ edge_dst, int* __restrict__ rp,
    int n_edges, int n_nodes) {
  const int v = blockIdx.x * blockDim.x + threadIdx.x;
  if (v > n_nodes) return;
  int lo = 0, hi = n_edges;
  while (lo < hi) {
    const int mid = (lo + hi) >> 1;
    if (edge_dst[mid] < v) lo = mid + 1; else hi = mid;
  }
  rp[v] = lo;
}

// Kernel 2: one wave per destination node. lane = feature index.
// Batch-load 64 edges' (src, weight) with coalesced lane loads, then
// broadcast via __shfl (register/LDS pipe, ~30cy) instead of per-iter
// global loads (~300cy). Plain store — no atomics, no memset needed
// (degree-0 nodes store 0).
__global__ __launch_bounds__(256) void gcn_gather_kernel(
    const float* __restrict__ feat,
    const float* __restrict__ edge_weight,
    const int* __restrict__ edge_src,
    const int* __restrict__ rp,
    float* __restrict__ out, int n_nodes) {
  const int wave = (blockIdx.x * blockDim.x + threadIdx.x) >> 6;
  const int lane = threadIdx.x & 63;
  if (wave >= n_nodes) return;

  const int e0 = rp[wave];
  const int e1 = rp[wave + 1];

  float acc0 = 0.0f, acc1 = 0.0f;

  for (int base = e0; base < e1; base += 64) {
    const int n = min(64, e1 - base);
    int   s = 0;
    float w = 0.0f;
    if (lane < n) {
      s = edge_src[base + lane];
      w = edge_weight[base + lane];
    }
    int i = 0;
    // 2-way software pipelining: two independent gathers in flight per step.
    for (; i + 1 < n; i += 2) {
      const int   s0 = __shfl(s, i);
      const int   s1 = __shfl(s, i + 1);
      const float w0 = __shfl(w, i);
      const float w1 = __shfl(w, i + 1);
      acc0 = fmaf(feat[(size_t)s0 * D_FEAT + lane], w0, acc0);
      acc1 = fmaf(feat[(size_t)s1 * D_FEAT + lane], w1, acc1);
    }
    if (i < n) {
      const int   s0 = __shfl(s, i);
      const float w0 = __shfl(w, i);
      acc0 = fmaf(feat[(size_t)s0 * D_FEAT + lane], w0, acc0);
    }
  }
  out[(size_t)wave * D_FEAT + lane] = acc0 + acc1;
}

extern "C" void kernel_launch(void* const* d_in, const int* in_sizes, int n_in,
                              void* d_out, int out_size, void* d_ws, size_t ws_size,
                              hipStream_t stream) {
  const float* feat        = (const float*)d_in[0];
  const float* edge_weight = (const float*)d_in[1];
  const int*   edge_src    = (const int*)d_in[2];
  const int*   edge_dst    = (const int*)d_in[3];
  float* out = (float*)d_out;

  const int n_edges = in_sizes[1];            // E = 1,250,000
  const int n_nodes = out_size / D_FEAT;      // N = 50,000

  int* rp = (int*)d_ws;                       // (N+1) ints

  const int bp_threads = n_nodes + 1;
  build_rowptr_kernel<<<(bp_threads + 255) / 256, 256, 0, stream>>>(
      edge_dst, rp, n_edges, n_nodes);

  const int total_threads = n_nodes * 64;     // one wave per node
  gcn_gather_kernel<<<(total_threads + 255) / 256, 256, 0, stream>>>(
      feat, edge_weight, edge_src, rp, out, n_nodes);
}

// Round 5
// 113.562 us; speedup vs baseline: 1.8194x; 1.1203x over previous
//
#include <hip/hip_runtime.h>

#define D_FEAT 64

// Kernel 1: row_ptr via edge-parallel boundary scatter (edge_dst sorted).
// rp[v] = first edge index with dst >= v, for v in [0, N]. Thread e covers
// node-gap (dst[e-1], dst[e]]; thread E covers (dst[E-1], N]. Every v is
// written exactly once. O(E) coalesced reads, no serial chains.
__global__ __launch_bounds__(256) void build_rowptr_scatter(
    const int* __restrict__ edge_dst, int* __restrict__ rp,
    int n_edges, int n_nodes) {
  const int e = blockIdx.x * blockDim.x + threadIdx.x;
  if (e > n_edges) return;
  const int d0 = (e == 0) ? -1 : edge_dst[e - 1];
  const int d1 = (e == n_edges) ? n_nodes : edge_dst[e];
  for (int v = d0 + 1; v <= d1; ++v) rp[v] = e;
}

// Kernel 2: one wave per destination node, 4 edges per load instruction.
// lane = 16*edge_slot + float4_index: one global_load_dwordx4 fetches four
// different 256B feat rows (64 lanes x 16B). 2x hand-unroll -> 8 row-gathers
// in flight per wave. Edge (src,w) batch-loaded coalesced then broadcast via
// __shfl. Lanes beyond the batch carry w=0, so tail slots contribute zero.
__global__ __launch_bounds__(256) void gcn_gather4(
    const float* __restrict__ feat,
    const float* __restrict__ ew,
    const int* __restrict__ esrc,
    const int* __restrict__ rp,
    float* __restrict__ out, int n_nodes) {
  const int wave = (blockIdx.x * blockDim.x + threadIdx.x) >> 6;
  const int lane = threadIdx.x & 63;
  if (wave >= n_nodes) return;
  const int sub = lane >> 4;   // edge slot 0..3
  const int fl  = lane & 15;   // float4 index within the 64-float row

  const int e0 = rp[wave];
  const int e1 = rp[wave + 1];

  float4 acc0 = {0.f, 0.f, 0.f, 0.f};
  float4 acc1 = {0.f, 0.f, 0.f, 0.f};

  const float4* feat4 = (const float4*)feat;

  for (int base = e0; base < e1; base += 64) {
    const int n = min(64, e1 - base);
    int   s = 0;
    float w = 0.0f;
    if (lane < n) {
      s = esrc[base + lane];
      w = ew[base + lane];
    }
    // i+4+sub <= 56+4+3 = 63: shfl index never exceeds 63.
    for (int i = 0; i < n; i += 8) {
      const int   sA = __shfl(s, i + sub);
      const float wA = __shfl(w, i + sub);
      const int   sB = __shfl(s, i + 4 + sub);
      const float wB = __shfl(w, i + 4 + sub);
      const float4 rA = feat4[(size_t)sA * 16 + fl];
      const float4 rB = feat4[(size_t)sB * 16 + fl];
      acc0.x = fmaf(rA.x, wA, acc0.x);
      acc0.y = fmaf(rA.y, wA, acc0.y);
      acc0.z = fmaf(rA.z, wA, acc0.z);
      acc0.w = fmaf(rA.w, wA, acc0.w);
      acc1.x = fmaf(rB.x, wB, acc1.x);
      acc1.y = fmaf(rB.y, wB, acc1.y);
      acc1.z = fmaf(rB.z, wB, acc1.z);
      acc1.w = fmaf(rB.w, wB, acc1.w);
    }
  }

  float4 acc;
  acc.x = acc0.x + acc1.x;
  acc.y = acc0.y + acc1.y;
  acc.z = acc0.z + acc1.z;
  acc.w = acc0.w + acc1.w;

  // Reduce the 4 edge-slot partials: lanes {l, l^16, l^32, l^48} share fl.
  acc.x += __shfl_xor(acc.x, 16);
  acc.y += __shfl_xor(acc.y, 16);
  acc.z += __shfl_xor(acc.z, 16);
  acc.w += __shfl_xor(acc.w, 16);
  acc.x += __shfl_xor(acc.x, 32);
  acc.y += __shfl_xor(acc.y, 32);
  acc.z += __shfl_xor(acc.z, 32);
  acc.w += __shfl_xor(acc.w, 32);

  if (lane < 16) {
    ((float4*)(out + (size_t)wave * D_FEAT))[fl] = acc;
  }
}

extern "C" void kernel_launch(void* const* d_in, const int* in_sizes, int n_in,
                              void* d_out, int out_size, void* d_ws, size_t ws_size,
                              hipStream_t stream) {
  const float* feat        = (const float*)d_in[0];
  const float* edge_weight = (const float*)d_in[1];
  const int*   edge_src    = (const int*)d_in[2];
  const int*   edge_dst    = (const int*)d_in[3];
  float* out = (float*)d_out;

  const int n_edges = in_sizes[1];            // E = 1,250,000
  const int n_nodes = out_size / D_FEAT;      // N = 50,000

  int* rp = (int*)d_ws;                       // (N+1) ints in scratch

  const int bp_threads = n_edges + 1;
  build_rowptr_scatter<<<(bp_threads + 255) / 256, 256, 0, stream>>>(
      edge_dst, rp, n_edges, n_nodes);

  const int total_threads = n_nodes * 64;     // one wave per node
  gcn_gather4<<<(total_threads + 255) / 256, 256, 0, stream>>>(
      feat, edge_weight, edge_src, rp, out, n_nodes);
}

// Round 6
// 113.212 us; speedup vs baseline: 1.8251x; 1.0031x over previous
//
#include <hip/hip_runtime.h>

#define D_FEAT 64

// Kernel 1: row_ptr via edge-parallel boundary scatter (edge_dst sorted).
// rp[v] = first edge index with dst >= v, for v in [0, N]. Thread e covers
// node-gap (dst[e-1], dst[e]]; thread E covers (dst[E-1], N]. Every v is
// written exactly once. O(E) coalesced reads, no serial chains.
__global__ __launch_bounds__(256) void build_rowptr_scatter(
    const int* __restrict__ edge_dst, int* __restrict__ rp,
    int n_edges, int n_nodes) {
  const int e = blockIdx.x * blockDim.x + threadIdx.x;
  if (e > n_edges) return;
  const int d0 = (e == 0) ? -1 : edge_dst[e - 1];
  const int d1 = (e == n_edges) ? n_nodes : edge_dst[e];
  for (int v = d0 + 1; v <= d1; ++v) rp[v] = e;
}

// Kernel 2: one wave per destination node. lane = 16*edge_slot + float4_idx:
// one global_load_dwordx4 fetches four different 256B feat rows. Inner loop
// covers 16 edge slots -> 4 independent dwordx4 gathers in flight per wave
// (2x the MLP of the previous round). Edge (src,w) batch-loaded coalesced
// once per 64-edge batch, broadcast via __shfl (all shfl sources are batch-
// invariant, so loads issue back-to-back). Slots beyond the batch carry w=0.
__global__ __launch_bounds__(256) void gcn_gather4(
    const float* __restrict__ feat,
    const float* __restrict__ ew,
    const int* __restrict__ esrc,
    const int* __restrict__ rp,
    float* __restrict__ out, int n_nodes) {
  const int wave = (blockIdx.x * blockDim.x + threadIdx.x) >> 6;
  const int lane = threadIdx.x & 63;
  if (wave >= n_nodes) return;
  const int sub = lane >> 4;   // edge slot 0..3
  const int fl  = lane & 15;   // float4 index within the 64-float row

  const int e0 = rp[wave];
  const int e1 = rp[wave + 1];

  float4 a0 = {0.f, 0.f, 0.f, 0.f};
  float4 a1 = {0.f, 0.f, 0.f, 0.f};
  float4 a2 = {0.f, 0.f, 0.f, 0.f};
  float4 a3 = {0.f, 0.f, 0.f, 0.f};

  const float4* feat4 = (const float4*)feat;

  for (int base = e0; base < e1; base += 64) {
    const int n = min(64, e1 - base);
    int   s = 0;
    float w = 0.0f;
    if (lane < n) {
      s = esrc[base + lane];
      w = ew[base + lane];
    }
    // i <= 48, so max shfl index = 48 + 12 + 3 = 63.
    for (int i = 0; i < n; i += 16) {
      const int   s0 = __shfl(s, i + sub);
      const float w0 = __shfl(w, i + sub);
      const int   s1 = __shfl(s, i + 4 + sub);
      const float w1 = __shfl(w, i + 4 + sub);
      const int   s2 = __shfl(s, i + 8 + sub);
      const float w2 = __shfl(w, i + 8 + sub);
      const int   s3 = __shfl(s, i + 12 + sub);
      const float w3 = __shfl(w, i + 12 + sub);
      const float4 r0 = feat4[(size_t)s0 * 16 + fl];
      const float4 r1 = feat4[(size_t)s1 * 16 + fl];
      const float4 r2 = feat4[(size_t)s2 * 16 + fl];
      const float4 r3 = feat4[(size_t)s3 * 16 + fl];
      a0.x = fmaf(r0.x, w0, a0.x); a0.y = fmaf(r0.y, w0, a0.y);
      a0.z = fmaf(r0.z, w0, a0.z); a0.w = fmaf(r0.w, w0, a0.w);
      a1.x = fmaf(r1.x, w1, a1.x); a1.y = fmaf(r1.y, w1, a1.y);
      a1.z = fmaf(r1.z, w1, a1.z); a1.w = fmaf(r1.w, w1, a1.w);
      a2.x = fmaf(r2.x, w2, a2.x); a2.y = fmaf(r2.y, w2, a2.y);
      a2.z = fmaf(r2.z, w2, a2.z); a2.w = fmaf(r2.w, w2, a2.w);
      a3.x = fmaf(r3.x, w3, a3.x); a3.y = fmaf(r3.y, w3, a3.y);
      a3.z = fmaf(r3.z, w3, a3.z); a3.w = fmaf(r3.w, w3, a3.w);
    }
  }

  float4 acc;
  acc.x = (a0.x + a1.x) + (a2.x + a3.x);
  acc.y = (a0.y + a1.y) + (a2.y + a3.y);
  acc.z = (a0.z + a1.z) + (a2.z + a3.z);
  acc.w = (a0.w + a1.w) + (a2.w + a3.w);

  // Reduce the 4 edge-slot partials: lanes {l, l^16, l^32, l^48} share fl.
  acc.x += __shfl_xor(acc.x, 16);
  acc.y += __shfl_xor(acc.y, 16);
  acc.z += __shfl_xor(acc.z, 16);
  acc.w += __shfl_xor(acc.w, 16);
  acc.x += __shfl_xor(acc.x, 32);
  acc.y += __shfl_xor(acc.y, 32);
  acc.z += __shfl_xor(acc.z, 32);
  acc.w += __shfl_xor(acc.w, 32);

  if (lane < 16) {
    ((float4*)(out + (size_t)wave * D_FEAT))[fl] = acc;
  }
}

extern "C" void kernel_launch(void* const* d_in, const int* in_sizes, int n_in,
                              void* d_out, int out_size, void* d_ws, size_t ws_size,
                              hipStream_t stream) {
  const float* feat        = (const float*)d_in[0];
  const float* edge_weight = (const float*)d_in[1];
  const int*   edge_src    = (const int*)d_in[2];
  const int*   edge_dst    = (const int*)d_in[3];
  float* out = (float*)d_out;

  const int n_edges = in_sizes[1];            // E = 1,250,000
  const int n_nodes = out_size / D_FEAT;      // N = 50,000

  int* rp = (int*)d_ws;                       // (N+1) ints in scratch

  const int bp_threads = n_edges + 1;
  build_rowptr_scatter<<<(bp_threads + 255) / 256, 256, 0, stream>>>(
      edge_dst, rp, n_edges, n_nodes);

  const int total_threads = n_nodes * 64;     // one wave per node
  gcn_gather4<<<(total_threads + 255) / 256, 256, 0, stream>>>(
      feat, edge_weight, edge_src, rp, out, n_nodes);
}